// Round 1
// baseline (121.904 us; speedup 1.0000x reference)
//
#include <hip/hip_runtime.h>
#include <hip/hip_bf16.h>
#include <stdint.h>

#define E_ 11
#define B_ 16
#define S_ 256
#define H_ 1024
#define L_ 32
#define GEPS 1e-4f

typedef __attribute__((ext_vector_type(8))) short short8;
typedef __attribute__((ext_vector_type(4))) float f32x4;

__device__ __forceinline__ unsigned short f2bf(float f) {
  unsigned u = __float_as_uint(f);
  unsigned r = (u + 0x7FFFu + ((u >> 16) & 1u)) >> 16;  // RNE
  return (unsigned short)r;
}
__device__ __forceinline__ float bf2f(unsigned short v) {
  return __uint_as_float(((unsigned)v) << 16);
}
__device__ __forceinline__ void gload_lds16(const void* g, void* l) {
  __builtin_amdgcn_global_load_lds(
      (const __attribute__((address_space(1))) unsigned int*)g,
      (__attribute__((address_space(3))) unsigned int*)l, 16, 0, 0);
}
__device__ __forceinline__ float sigf(float x) { return 1.0f / (1.0f + expf(-x)); }

// ---------------- gates: lang_id soft-argmax + top-hat gate [E,B] ----------------
__global__ void gates_kernel(const float* __restrict__ logits, float* __restrict__ gates) {
  int b = threadIdx.x;
  if (b >= B_) return;
  float lv[E_];
  float m = -1e30f;
  for (int i = 0; i < E_; ++i) { lv[i] = logits[b * E_ + i]; m = fmaxf(m, lv[i]); }
  float den = 0.f, num = 0.f;
  for (int i = 0; i < E_; ++i) {
    float z = expf((lv[i] - m) * 1000.0f);
    den += z; num += z * (float)i;
  }
  float lang = num / den;
  for (int e = 0; e < E_; ++e) {
    float ie = (float)e;
    gates[e * B_ + b] = sigf((lang - (ie - 0.5f)) * 8.0f) * sigf(((ie + 0.5f) - lang) * 8.0f);
  }
}

// ---------------- cvt x -> bf16 (layout unchanged [B,S,H]) ----------------
__global__ void cvt_x_kernel(const float* __restrict__ x, unsigned short* __restrict__ xbf) {
  int i = (blockIdx.x * 256 + threadIdx.x) * 8;
  float4 f0 = *(const float4*)(x + i);
  float4 f1 = *(const float4*)(x + i + 4);
  short8 o;
  o[0] = (short)f2bf(f0.x); o[1] = (short)f2bf(f0.y);
  o[2] = (short)f2bf(f0.z); o[3] = (short)f2bf(f0.w);
  o[4] = (short)f2bf(f1.x); o[5] = (short)f2bf(f1.y);
  o[6] = (short)f2bf(f1.z); o[7] = (short)f2bf(f1.w);
  *(short8*)(xbf + i) = o;
}

// ---------------- cvt+transpose W1 [E][k][d] -> W1T bf16 [E][d][k], skip inactive ----------------
__global__ void cvt_w1_kernel(const float* __restrict__ W1, const float* __restrict__ gates,
                              unsigned short* __restrict__ W1T) {
  int e = blockIdx.z, k0 = blockIdx.y * 64, d0 = blockIdx.x * 64;
  bool act = false;
  for (int b = 0; b < B_; ++b) act |= (gates[e * B_ + b] > GEPS);
  if (!act) return;
  __shared__ float t[64][65];
  int tid = threadIdx.x;
  int kr = tid >> 2, dc = (tid & 3) * 16;
  const float* src = W1 + ((size_t)e << 20) + (size_t)(k0 + kr) * H_ + d0 + dc;
  #pragma unroll
  for (int q = 0; q < 4; ++q) {
    float4 v = *(const float4*)(src + q * 4);
    t[kr][dc + q * 4 + 0] = v.x; t[kr][dc + q * 4 + 1] = v.y;
    t[kr][dc + q * 4 + 2] = v.z; t[kr][dc + q * 4 + 3] = v.w;
  }
  __syncthreads();
  int dr = tid >> 2, kc = (tid & 3) * 16;
  short8 v0, v1;
  #pragma unroll
  for (int j = 0; j < 8; ++j) v0[j] = (short)f2bf(t[kc + j][dr]);
  #pragma unroll
  for (int j = 0; j < 8; ++j) v1[j] = (short)f2bf(t[kc + 8 + j][dr]);
  unsigned short* dst = W1T + ((size_t)e << 20) + (size_t)(d0 + dr) * H_ + k0 + kc;
  *(short8*)(dst) = v0;
  *(short8*)(dst + 8) = v1;
}

// ---------------- cvt+transpose W2 [E][k][l] -> W2T bf16 [E][l][k] ----------------
__global__ void cvt_w2_kernel(const float* __restrict__ W2, const float* __restrict__ gates,
                              unsigned short* __restrict__ W2T) {
  int e = blockIdx.y, k0 = blockIdx.x * 64;
  bool act = false;
  for (int b = 0; b < B_; ++b) act |= (gates[e * B_ + b] > GEPS);
  if (!act) return;
  __shared__ float t[64][33];
  int tid = threadIdx.x;
  int kr = tid >> 2, lc = (tid & 3) * 8;
  const float* src = W2 + (size_t)e * H_ * L_ + (size_t)(k0 + kr) * L_ + lc;
  float4 a = *(const float4*)(src);
  float4 b = *(const float4*)(src + 4);
  t[kr][lc + 0] = a.x; t[kr][lc + 1] = a.y; t[kr][lc + 2] = a.z; t[kr][lc + 3] = a.w;
  t[kr][lc + 4] = b.x; t[kr][lc + 5] = b.y; t[kr][lc + 6] = b.z; t[kr][lc + 7] = b.w;
  __syncthreads();
  int lr = tid >> 3, kc = (tid & 7) * 8;
  short8 v;
  #pragma unroll
  for (int j = 0; j < 8; ++j) v[j] = (short)f2bf(t[kc + j][lr]);
  *(short8*)(W2T + (size_t)(e * L_ + lr) * H_ + k0 + kc) = v;
}

// ---------------- fused gated FFN: per (e,b,64-row slice), MFMA bf16 ----------------
// LDS: A tile [64s][32k] x2 (8KB), B tile [256d][32k] x2 (32KB). Row-pair packed,
// XOR-swizzled 16B chunks for conflict-free ds_read_b128; staged via global_load_lds
// with inverse-swizzled per-lane global sources (dest is lane-linear).
__global__ __launch_bounds__(256, 2) void ffn_kernel(
    const unsigned short* __restrict__ xbf, const unsigned short* __restrict__ W1T,
    const unsigned short* __restrict__ W2T, const float* __restrict__ b1,
    const float* __restrict__ b2, const float* __restrict__ gates,
    float* __restrict__ out) {
  int bid = blockIdx.x;
  int x8 = bid & 7, j = bid >> 3;          // pin expert -> XCD (bid%8)
  int e = x8 + 8 * (j >= 64);
  if (e >= E_) return;
  int r = j & 63;
  int b = r >> 2, sblk = r & 3, s0 = sblk * 64;
  float g = gates[e * B_ + b];
  if (g < GEPS) return;

  __shared__ __align__(16) char smem[40960];
  char* sA = smem;         // 2 x 4096
  char* sB = smem + 8192;  // 2 x 16384

  int tid = threadIdx.x;
  int w = tid >> 6, l = tid & 63;
  int l15 = l & 15, l4 = l >> 4;

  f32x4 tacc[4][2];
  #pragma unroll
  for (int mf = 0; mf < 4; ++mf)
    #pragma unroll
    for (int nf = 0; nf < 2; ++nf) tacc[mf][nf] = f32x4{0.f, 0.f, 0.f, 0.f};

  auto stage = [&](int buf, int dt, int kt) {
    {  // A tile: 256 chunks, 1 per lane
      int c = tid;
      int p = c >> 3, slot = c & 7;
      int u = slot ^ (p & 7);
      int srow = p * 2 + (u >> 2), kc = u & 3;
      const unsigned short* src =
          xbf + (size_t)(b * S_ + s0 + srow) * H_ + kt * 32 + kc * 8;
      gload_lds16(src, sA + buf * 4096 + c * 16);
    }
    #pragma unroll
    for (int jj = 0; jj < 4; ++jj) {  // B tile: 1024 chunks, 4 per lane
      int c = jj * 256 + tid;
      int p = c >> 3, slot = c & 7;
      int u = slot ^ (p & 7);
      int d = p * 2 + (u >> 2), kc = u & 3;
      const unsigned short* src =
          W1T + ((size_t)e * H_ + dt * 256 + d) * H_ + kt * 32 + kc * 8;
      gload_lds16(src, sB + buf * 16384 + c * 16);
    }
  };

  for (int dt = 0; dt < 4; ++dt) {
    float b1v[4];
    #pragma unroll
    for (int nf = 0; nf < 4; ++nf)
      b1v[nf] = b1[e * H_ + dt * 256 + w * 64 + nf * 16 + l15];

    f32x4 acc[4][4];
    #pragma unroll
    for (int mf = 0; mf < 4; ++mf)
      #pragma unroll
      for (int nf = 0; nf < 4; ++nf) acc[mf][nf] = f32x4{0.f, 0.f, 0.f, 0.f};

    stage(0, dt, 0);
    __syncthreads();
    for (int kt = 0; kt < 32; ++kt) {
      int cur = kt & 1;
      if (kt < 31) stage(cur ^ 1, dt, kt + 1);
      short8 af[4], bf[4];
      #pragma unroll
      for (int mf = 0; mf < 4; ++mf) {
        int row = mf * 16 + l15;
        int p = row >> 1;
        int slot = (((row & 1) * 4) + l4) ^ (p & 7);
        af[mf] = *(const short8*)(sA + cur * 4096 + p * 128 + slot * 16);
      }
      #pragma unroll
      for (int nf = 0; nf < 4; ++nf) {
        int d = w * 64 + nf * 16 + l15;
        int p = d >> 1;
        int slot = (((d & 1) * 4) + l4) ^ (p & 7);
        bf[nf] = *(const short8*)(sB + cur * 16384 + p * 128 + slot * 16);
      }
      #pragma unroll
      for (int mf = 0; mf < 4; ++mf)
        #pragma unroll
        for (int nf = 0; nf < 4; ++nf)
          acc[mf][nf] =
              __builtin_amdgcn_mfma_f32_16x16x32_bf16(af[mf], bf[nf], acc[mf][nf], 0, 0, 0);
      __syncthreads();
    }

    // relu(acc + b1) -> bf16 P strip in LDS (overlay on sB, per-wave private 8KB)
    char* P = sB + w * 8192;
    #pragma unroll
    for (int mf = 0; mf < 4; ++mf)
      #pragma unroll
      for (int nf = 0; nf < 4; ++nf)
        #pragma unroll
        for (int rr = 0; rr < 4; ++rr) {
          int row = mf * 16 + l4 * 4 + rr;
          int col = nf * 16 + l15;
          float v = fmaxf(acc[mf][nf][rr] + b1v[nf], 0.f);
          *(unsigned short*)(P + row * 128 + (((col >> 3) ^ (row & 7)) * 16) +
                             (col & 7) * 2) = f2bf(v);
        }
    asm volatile("s_waitcnt lgkmcnt(0)" ::: "memory");

    // stage 2: t += P @ W2T-slice
    #pragma unroll
    for (int kk = 0; kk < 2; ++kk) {
      short8 ap[4], bw[2];
      #pragma unroll
      for (int mf = 0; mf < 4; ++mf) {
        int row = mf * 16 + l15;
        int ch = kk * 4 + l4;
        ap[mf] = *(const short8*)(P + row * 128 + ((ch ^ (row & 7)) * 16));
      }
      #pragma unroll
      for (int nf = 0; nf < 2; ++nf)
        bw[nf] = *(const short8*)(W2T + (size_t)(e * L_ + nf * 16 + l15) * H_ +
                                  dt * 256 + w * 64 + kk * 32 + l4 * 8);
      #pragma unroll
      for (int mf = 0; mf < 4; ++mf)
        #pragma unroll
        for (int nf = 0; nf < 2; ++nf)
          tacc[mf][nf] =
              __builtin_amdgcn_mfma_f32_16x16x32_bf16(ap[mf], bw[nf], tacc[mf][nf], 0, 0, 0);
    }
    __syncthreads();
  }

  // cross-wave reduce of t, + b2, * gate, atomicAdd to out
  float* Tred = (float*)sB;
  #pragma unroll
  for (int mf = 0; mf < 4; ++mf)
    #pragma unroll
    for (int nf = 0; nf < 2; ++nf)
      #pragma unroll
      for (int rr = 0; rr < 4; ++rr) {
        int row = mf * 16 + l4 * 4 + rr;
        int col = nf * 16 + l15;
        Tred[w * 2048 + row * 32 + col] = tacc[mf][nf][rr];
      }
  __syncthreads();
  #pragma unroll
  for (int jj = 0; jj < 8; ++jj) {
    int ei = tid + jj * 256;
    int srow = ei >> 5, lcol = ei & 31;
    float sum = Tred[ei] + Tred[2048 + ei] + Tred[4096 + ei] + Tred[6144 + ei];
    sum += b2[e * L_ + lcol];
    atomicAdd(out + (size_t)(b * S_ + s0 + srow) * L_ + lcol, g * sum);
  }
}

// ---------------- fp32 fallback (no workspace needed) ----------------
__global__ void fb_kernel(const float* __restrict__ x, const float* __restrict__ logits,
                          const float* __restrict__ W1, const float* __restrict__ b1,
                          const float* __restrict__ W2, const float* __restrict__ b2,
                          float* __restrict__ out) {
  int bid = blockIdx.x;
  int e = bid >> 9;
  int r = bid & 511;
  int b = r >> 5, st = r & 31, s0 = st * 8;
  float lv[E_];
  float m = -1e30f;
  for (int i = 0; i < E_; ++i) { lv[i] = logits[b * E_ + i]; m = fmaxf(m, lv[i]); }
  float den = 0.f, num = 0.f;
  for (int i = 0; i < E_; ++i) {
    float z = expf((lv[i] - m) * 1000.0f);
    den += z; num += z * (float)i;
  }
  float lang = num / den;
  float fe = (float)e;
  float g = sigf((lang - (fe - 0.5f)) * 8.0f) * sigf(((fe + 0.5f) - lang) * 8.0f);
  if (g < GEPS) return;

  __shared__ float xs[8][H_];
  __shared__ unsigned short hs[8][H_];
  int tid = threadIdx.x;
  for (int jj = 0; jj < 32; ++jj) {
    int idx = tid + jj * 256;
    int s = idx >> 10, k = idx & 1023;
    xs[s][k] = x[(size_t)(b * S_ + s0 + s) * H_ + k];
  }
  __syncthreads();
  for (int q = 0; q < 4; ++q) {
    int d = tid + q * 256;
    float a[8];
    #pragma unroll
    for (int s = 0; s < 8; ++s) a[s] = 0.f;
    for (int k = 0; k < H_; ++k) {
      float wv = W1[((size_t)e << 20) + (size_t)k * H_ + d];
      #pragma unroll
      for (int s = 0; s < 8; ++s) a[s] += xs[s][k] * wv;
    }
    float bv = b1[e * H_ + d];
    #pragma unroll
    for (int s = 0; s < 8; ++s) hs[s][d] = f2bf(fmaxf(a[s] + bv, 0.f));
  }
  __syncthreads();
  int s = tid >> 5, lcol = tid & 31;
  float acc = 0.f;
  for (int d = 0; d < H_; ++d)
    acc += bf2f(hs[s][d]) * W2[(size_t)(e * H_ + d) * L_ + lcol];
  acc += b2[e * L_ + lcol];
  atomicAdd(out + (size_t)(b * S_ + s0 + s) * L_ + lcol, g * acc);
}

extern "C" void kernel_launch(void* const* d_in, const int* in_sizes, int n_in,
                              void* d_out, int out_size, void* d_ws, size_t ws_size,
                              hipStream_t stream) {
  (void)in_sizes; (void)n_in;
  const float* x  = (const float*)d_in[0];
  const float* lg = (const float*)d_in[1];
  const float* W1 = (const float*)d_in[2];
  const float* b1 = (const float*)d_in[3];
  const float* W2 = (const float*)d_in[4];
  const float* b2 = (const float*)d_in[5];
  float* out = (float*)d_out;

  hipMemsetAsync(d_out, 0, (size_t)out_size * sizeof(float), stream);

  const size_t OFF_G = 0;
  const size_t OFF_X = 4096;                       // 8 MB bf16 x
  const size_t OFF_W1 = OFF_X + 8388608;           // 22 MB bf16 W1T
  const size_t OFF_W2 = OFF_W1 + 23068672;         // 704 KB bf16 W2T
  const size_t WS_NEED = OFF_W2 + 720896;

  if (ws_size >= WS_NEED) {
    float* gates = (float*)((char*)d_ws + OFF_G);
    unsigned short* xbf = (unsigned short*)((char*)d_ws + OFF_X);
    unsigned short* W1T = (unsigned short*)((char*)d_ws + OFF_W1);
    unsigned short* W2T = (unsigned short*)((char*)d_ws + OFF_W2);
    gates_kernel<<<1, 64, 0, stream>>>(lg, gates);
    cvt_x_kernel<<<2048, 256, 0, stream>>>(x, xbf);
    cvt_w1_kernel<<<dim3(16, 16, E_), 256, 0, stream>>>(W1, gates, W1T);
    cvt_w2_kernel<<<dim3(16, E_), 256, 0, stream>>>(W2, gates, W2T);
    ffn_kernel<<<1024, 256, 0, stream>>>(xbf, W1T, W2T, b1, b2, gates, out);
  } else {
    fb_kernel<<<E_ * B_ * (S_ / 8), 256, 0, stream>>>(x, lg, W1, b1, W2, b2, out);
  }
}

// Round 3
// 84.528 us; speedup vs baseline: 1.4422x; 1.4422x over previous
//
#include <hip/hip_runtime.h>
#include <hip/hip_bf16.h>
#include <stdint.h>

#define E_ 11
#define B_ 16
#define S_ 256
#define H_ 1024
#define L_ 32
#define GEPS 1e-4f

typedef __attribute__((ext_vector_type(8))) short short8;
typedef __attribute__((ext_vector_type(4))) float f32x4;

__device__ __forceinline__ unsigned short f2bf(float f) {
  unsigned u = __float_as_uint(f);
  unsigned r = (u + 0x7FFFu + ((u >> 16) & 1u)) >> 16;  // RNE
  return (unsigned short)r;
}
__device__ __forceinline__ float bf2f(unsigned short v) {
  return __uint_as_float(((unsigned)v) << 16);
}
__device__ __forceinline__ void gload_lds16(const void* g, void* l) {
  __builtin_amdgcn_global_load_lds(
      (const __attribute__((address_space(1))) unsigned int*)g,
      (__attribute__((address_space(3))) unsigned int*)l, 16, 0, 0);
}
__device__ __forceinline__ float sigf(float x) { return 1.0f / (1.0f + expf(-x)); }

// ---------------- gates: lang_id soft-argmax + top-hat gate [E,B] ----------------
__global__ void gates_kernel(const float* __restrict__ logits, float* __restrict__ gates) {
  int b = threadIdx.x;
  if (b >= B_) return;
  float lv[E_];
  float m = -1e30f;
  for (int i = 0; i < E_; ++i) { lv[i] = logits[b * E_ + i]; m = fmaxf(m, lv[i]); }
  float den = 0.f, num = 0.f;
  for (int i = 0; i < E_; ++i) {
    float z = expf((lv[i] - m) * 1000.0f);
    den += z; num += z * (float)i;
  }
  float lang = num / den;
  for (int e = 0; e < E_; ++e) {
    float ie = (float)e;
    gates[e * B_ + b] = sigf((lang - (ie - 0.5f)) * 8.0f) * sigf(((ie + 0.5f) - lang) * 8.0f);
  }
}

// ---------------- cvt x -> bf16 (layout unchanged [B,S,H]) ----------------
__global__ void cvt_x_kernel(const float* __restrict__ x, unsigned short* __restrict__ xbf) {
  int i = (blockIdx.x * 256 + threadIdx.x) * 8;
  float4 f0 = *(const float4*)(x + i);
  float4 f1 = *(const float4*)(x + i + 4);
  short8 o;
  o[0] = (short)f2bf(f0.x); o[1] = (short)f2bf(f0.y);
  o[2] = (short)f2bf(f0.z); o[3] = (short)f2bf(f0.w);
  o[4] = (short)f2bf(f1.x); o[5] = (short)f2bf(f1.y);
  o[6] = (short)f2bf(f1.z); o[7] = (short)f2bf(f1.w);
  *(short8*)(xbf + i) = o;
}

// ---------------- cvt+transpose W1 [E][k][d] -> W1T bf16 [E][d][k], skip inactive ----------------
__global__ void cvt_w1_kernel(const float* __restrict__ W1, const float* __restrict__ gates,
                              unsigned short* __restrict__ W1T) {
  int e = blockIdx.z, k0 = blockIdx.y * 64, d0 = blockIdx.x * 64;
  bool act = false;
  for (int b = 0; b < B_; ++b) act |= (gates[e * B_ + b] > GEPS);
  if (!act) return;
  __shared__ float t[64][65];
  int tid = threadIdx.x;
  int kr = tid >> 2, dc = (tid & 3) * 16;
  const float* src = W1 + ((size_t)e << 20) + (size_t)(k0 + kr) * H_ + d0 + dc;
  #pragma unroll
  for (int q = 0; q < 4; ++q) {
    float4 v = *(const float4*)(src + q * 4);
    t[kr][dc + q * 4 + 0] = v.x; t[kr][dc + q * 4 + 1] = v.y;
    t[kr][dc + q * 4 + 2] = v.z; t[kr][dc + q * 4 + 3] = v.w;
  }
  __syncthreads();
  int dr = tid >> 2, kc = (tid & 3) * 16;
  short8 v0, v1;
  #pragma unroll
  for (int j = 0; j < 8; ++j) v0[j] = (short)f2bf(t[kc + j][dr]);
  #pragma unroll
  for (int j = 0; j < 8; ++j) v1[j] = (short)f2bf(t[kc + 8 + j][dr]);
  unsigned short* dst = W1T + ((size_t)e << 20) + (size_t)(d0 + dr) * H_ + k0 + kc;
  *(short8*)(dst) = v0;
  *(short8*)(dst + 8) = v1;
}

// ---------------- cvt+transpose W2 [E][k][l] -> W2T bf16 [E][l][k] ----------------
__global__ void cvt_w2_kernel(const float* __restrict__ W2, const float* __restrict__ gates,
                              unsigned short* __restrict__ W2T) {
  int e = blockIdx.y, k0 = blockIdx.x * 64;
  bool act = false;
  for (int b = 0; b < B_; ++b) act |= (gates[e * B_ + b] > GEPS);
  if (!act) return;
  __shared__ float t[64][33];
  int tid = threadIdx.x;
  int kr = tid >> 2, lc = (tid & 3) * 8;
  const float* src = W2 + (size_t)e * H_ * L_ + (size_t)(k0 + kr) * L_ + lc;
  float4 a = *(const float4*)(src);
  float4 b = *(const float4*)(src + 4);
  t[kr][lc + 0] = a.x; t[kr][lc + 1] = a.y; t[kr][lc + 2] = a.z; t[kr][lc + 3] = a.w;
  t[kr][lc + 4] = b.x; t[kr][lc + 5] = b.y; t[kr][lc + 6] = b.z; t[kr][lc + 7] = b.w;
  __syncthreads();
  int lr = tid >> 3, kc = (tid & 7) * 8;
  short8 v;
  #pragma unroll
  for (int j = 0; j < 8; ++j) v[j] = (short)f2bf(t[kc + j][lr]);
  *(short8*)(W2T + (size_t)(e * L_ + lr) * H_ + k0 + kc) = v;
}

// ---------------- fused gated FFN: one block per (e, dt, b, 64-row slice) ----------------
// dt-split across blocks for 4x parallelism; XCD pinned per (e,dt) unit so the 16
// (b,sblk) readers of one 512KB W1T slice share one L2. Partial t atomicAdd'ed;
// b2 added only by dt==0 blocks. Grid MUST be 8*384 (6 ui levels x 64 sub x 8 xcd).
__global__ __launch_bounds__(256, 4) void ffn_kernel(
    const unsigned short* __restrict__ xbf, const unsigned short* __restrict__ W1T,
    const unsigned short* __restrict__ W2T, const float* __restrict__ b1,
    const float* __restrict__ b2, const float* __restrict__ gates,
    float* __restrict__ out) {
  int bid = blockIdx.x;
  int x = bid & 7;          // XCD lane
  int m = bid >> 3;         // [0,384)
  int ui = m >> 6;          // [0,6)
  int u = x + 8 * ui;       // (e,dt) unit, pinned to XCD u%8 == x
  if (u >= E_ * 4) return;
  int e = u >> 2, dt = u & 3;
  int sub = m & 63;
  int b = sub >> 2, sblk = sub & 3, s0 = sblk * 64;
  float g = gates[e * B_ + b];
  if (g < GEPS) return;

  __shared__ __align__(16) char smem[40960];
  char* sA = smem;         // 2 x 4096
  char* sB = smem + 8192;  // 2 x 16384

  int tid = threadIdx.x;
  int w = tid >> 6, l = tid & 63;
  int l15 = l & 15, l4 = l >> 4;

  auto stage = [&](int buf, int kt) {
    {  // A tile: 256 chunks, 1 per lane
      int c = tid;
      int p = c >> 3, slot = c & 7;
      int uu = slot ^ (p & 7);
      int srow = p * 2 + (uu >> 2), kc = uu & 3;
      const unsigned short* src =
          xbf + (size_t)(b * S_ + s0 + srow) * H_ + kt * 32 + kc * 8;
      gload_lds16(src, sA + buf * 4096 + c * 16);
    }
    #pragma unroll
    for (int jj = 0; jj < 4; ++jj) {  // B tile: 1024 chunks, 4 per lane
      int c = jj * 256 + tid;
      int p = c >> 3, slot = c & 7;
      int uu = slot ^ (p & 7);
      int d = p * 2 + (uu >> 2), kc = uu & 3;
      const unsigned short* src =
          W1T + ((size_t)e * H_ + dt * 256 + d) * H_ + kt * 32 + kc * 8;
      gload_lds16(src, sB + buf * 16384 + c * 16);
    }
  };

  float b1v[4];
  #pragma unroll
  for (int nf = 0; nf < 4; ++nf)
    b1v[nf] = b1[e * H_ + dt * 256 + w * 64 + nf * 16 + l15];

  f32x4 acc[4][4];
  #pragma unroll
  for (int mf = 0; mf < 4; ++mf)
    #pragma unroll
    for (int nf = 0; nf < 4; ++nf) acc[mf][nf] = f32x4{0.f, 0.f, 0.f, 0.f};

  stage(0, 0);
  __syncthreads();
  for (int kt = 0; kt < 32; ++kt) {
    int cur = kt & 1;
    if (kt < 31) stage(cur ^ 1, kt + 1);
    short8 af[4], bf[4];
    #pragma unroll
    for (int mf = 0; mf < 4; ++mf) {
      int row = mf * 16 + l15;
      int p = row >> 1;
      int slot = (((row & 1) * 4) + l4) ^ (p & 7);
      af[mf] = *(const short8*)(sA + cur * 4096 + p * 128 + slot * 16);
    }
    #pragma unroll
    for (int nf = 0; nf < 4; ++nf) {
      int d = w * 64 + nf * 16 + l15;
      int p = d >> 1;
      int slot = (((d & 1) * 4) + l4) ^ (p & 7);
      bf[nf] = *(const short8*)(sB + cur * 16384 + p * 128 + slot * 16);
    }
    #pragma unroll
    for (int mf = 0; mf < 4; ++mf)
      #pragma unroll
      for (int nf = 0; nf < 4; ++nf)
        acc[mf][nf] =
            __builtin_amdgcn_mfma_f32_16x16x32_bf16(af[mf], bf[nf], acc[mf][nf], 0, 0, 0);
    __syncthreads();
  }

  // relu(acc + b1) -> bf16 P strip in LDS (overlay on sB, per-wave private 8KB)
  char* P = sB + w * 8192;
  #pragma unroll
  for (int mf = 0; mf < 4; ++mf)
    #pragma unroll
    for (int nf = 0; nf < 4; ++nf)
      #pragma unroll
      for (int rr = 0; rr < 4; ++rr) {
        int row = mf * 16 + l4 * 4 + rr;
        int col = nf * 16 + l15;
        float v = fmaxf(acc[mf][nf][rr] + b1v[nf], 0.f);
        *(unsigned short*)(P + row * 128 + (((col >> 3) ^ (row & 7)) * 16) +
                           (col & 7) * 2) = f2bf(v);
      }
  asm volatile("s_waitcnt lgkmcnt(0)" ::: "memory");

  // stage 2: t_partial = P @ W2T-slice (K = this wave's 64 d's)
  f32x4 tacc[4][2];
  #pragma unroll
  for (int mf = 0; mf < 4; ++mf)
    #pragma unroll
    for (int nf = 0; nf < 2; ++nf) tacc[mf][nf] = f32x4{0.f, 0.f, 0.f, 0.f};
  #pragma unroll
  for (int kk = 0; kk < 2; ++kk) {
    short8 ap[4], bw[2];
    #pragma unroll
    for (int mf = 0; mf < 4; ++mf) {
      int row = mf * 16 + l15;
      int ch = kk * 4 + l4;
      ap[mf] = *(const short8*)(P + row * 128 + ((ch ^ (row & 7)) * 16));
    }
    #pragma unroll
    for (int nf = 0; nf < 2; ++nf)
      bw[nf] = *(const short8*)(W2T + (size_t)(e * L_ + nf * 16 + l15) * H_ +
                                dt * 256 + w * 64 + kk * 32 + l4 * 8);
    #pragma unroll
    for (int mf = 0; mf < 4; ++mf)
      #pragma unroll
      for (int nf = 0; nf < 2; ++nf)
        tacc[mf][nf] =
            __builtin_amdgcn_mfma_f32_16x16x32_bf16(ap[mf], bw[nf], tacc[mf][nf], 0, 0, 0);
  }

  // cross-wave reduce of t_partial, (+ b2 if dt==0), * gate, atomicAdd to out
  float* Tred = (float*)sB;
  #pragma unroll
  for (int mf = 0; mf < 4; ++mf)
    #pragma unroll
    for (int nf = 0; nf < 2; ++nf)
      #pragma unroll
      for (int rr = 0; rr < 4; ++rr) {
        int row = mf * 16 + l4 * 4 + rr;
        int col = nf * 16 + l15;
        Tred[w * 2048 + row * 32 + col] = tacc[mf][nf][rr];
      }
  __syncthreads();
  #pragma unroll
  for (int jj = 0; jj < 8; ++jj) {
    int ei = tid + jj * 256;
    int srow = ei >> 5, lcol = ei & 31;
    float sum = Tred[ei] + Tred[2048 + ei] + Tred[4096 + ei] + Tred[6144 + ei];
    if (dt == 0) sum += b2[e * L_ + lcol];
    atomicAdd(out + (size_t)(b * S_ + s0 + srow) * L_ + lcol, g * sum);
  }
}

// ---------------- fp32 fallback (no workspace needed) ----------------
__global__ void fb_kernel(const float* __restrict__ x, const float* __restrict__ logits,
                          const float* __restrict__ W1, const float* __restrict__ b1,
                          const float* __restrict__ W2, const float* __restrict__ b2,
                          float* __restrict__ out) {
  int bid = blockIdx.x;
  int e = bid >> 9;
  int r = bid & 511;
  int b = r >> 5, st = r & 31, s0 = st * 8;
  float lv[E_];
  float m = -1e30f;
  for (int i = 0; i < E_; ++i) { lv[i] = logits[b * E_ + i]; m = fmaxf(m, lv[i]); }
  float den = 0.f, num = 0.f;
  for (int i = 0; i < E_; ++i) {
    float z = expf((lv[i] - m) * 1000.0f);
    den += z; num += z * (float)i;
  }
  float lang = num / den;
  float fe = (float)e;
  float g = sigf((lang - (fe - 0.5f)) * 8.0f) * sigf(((fe + 0.5f) - lang) * 8.0f);
  if (g < GEPS) return;

  __shared__ float xs[8][H_];
  __shared__ unsigned short hs[8][H_];
  int tid = threadIdx.x;
  for (int jj = 0; jj < 32; ++jj) {
    int idx = tid + jj * 256;
    int s = idx >> 10, k = idx & 1023;
    xs[s][k] = x[(size_t)(b * S_ + s0 + s) * H_ + k];
  }
  __syncthreads();
  for (int q = 0; q < 4; ++q) {
    int d = tid + q * 256;
    float a[8];
    #pragma unroll
    for (int s = 0; s < 8; ++s) a[s] = 0.f;
    for (int k = 0; k < H_; ++k) {
      float wv = W1[((size_t)e << 20) + (size_t)k * H_ + d];
      #pragma unroll
      for (int s = 0; s < 8; ++s) a[s] += xs[s][k] * wv;
    }
    float bv = b1[e * H_ + d];
    #pragma unroll
    for (int s = 0; s < 8; ++s) hs[s][d] = f2bf(fmaxf(a[s] + bv, 0.f));
  }
  __syncthreads();
  int s = tid >> 5, lcol = tid & 31;
  float acc = 0.f;
  for (int d = 0; d < H_; ++d)
    acc += bf2f(hs[s][d]) * W2[(size_t)(e * H_ + d) * L_ + lcol];
  acc += b2[e * L_ + lcol];
  atomicAdd(out + (size_t)(b * S_ + s0 + s) * L_ + lcol, g * acc);
}

extern "C" void kernel_launch(void* const* d_in, const int* in_sizes, int n_in,
                              void* d_out, int out_size, void* d_ws, size_t ws_size,
                              hipStream_t stream) {
  (void)in_sizes; (void)n_in;
  const float* x  = (const float*)d_in[0];
  const float* lg = (const float*)d_in[1];
  const float* W1 = (const float*)d_in[2];
  const float* b1 = (const float*)d_in[3];
  const float* W2 = (const float*)d_in[4];
  const float* b2 = (const float*)d_in[5];
  float* out = (float*)d_out;

  hipMemsetAsync(d_out, 0, (size_t)out_size * sizeof(float), stream);

  const size_t OFF_G = 0;
  const size_t OFF_X = 4096;                       // 8 MB bf16 x
  const size_t OFF_W1 = OFF_X + 8388608;           // 22 MB bf16 W1T
  const size_t OFF_W2 = OFF_W1 + 23068672;         // 704 KB bf16 W2T
  const size_t WS_NEED = OFF_W2 + 720896;

  if (ws_size >= WS_NEED) {
    float* gates = (float*)((char*)d_ws + OFF_G);
    unsigned short* xbf = (unsigned short*)((char*)d_ws + OFF_X);
    unsigned short* W1T = (unsigned short*)((char*)d_ws + OFF_W1);
    unsigned short* W2T = (unsigned short*)((char*)d_ws + OFF_W2);
    gates_kernel<<<1, 64, 0, stream>>>(lg, gates);
    cvt_x_kernel<<<2048, 256, 0, stream>>>(x, xbf);
    cvt_w1_kernel<<<dim3(16, 16, E_), 256, 0, stream>>>(W1, gates, W1T);
    cvt_w2_kernel<<<dim3(16, E_), 256, 0, stream>>>(W2, gates, W2T);
    // 8 XCD lanes x 384: unit u=(e,dt) pinned to XCD u%8, 64 (b,sblk) blocks per unit
    ffn_kernel<<<8 * 384, 256, 0, stream>>>(xbf, W1T, W2T, b1, b2, gates, out);
  } else {
    fb_kernel<<<E_ * B_ * (S_ / 8), 256, 0, stream>>>(x, lg, W1, b1, W2, b2, out);
  }
}

// Round 4
// 81.779 us; speedup vs baseline: 1.4907x; 1.0336x over previous
//
#include <hip/hip_runtime.h>
#include <hip/hip_bf16.h>
#include <stdint.h>

#define E_ 11
#define B_ 16
#define S_ 256
#define H_ 1024
#define L_ 32
#define GEPS 1e-4f

typedef __attribute__((ext_vector_type(8))) short short8;
typedef __attribute__((ext_vector_type(4))) float f32x4;

__device__ __forceinline__ unsigned short f2bf(float f) {
  unsigned u = __float_as_uint(f);
  unsigned r = (u + 0x7FFFu + ((u >> 16) & 1u)) >> 16;  // RNE
  return (unsigned short)r;
}
__device__ __forceinline__ float bf2f(unsigned short v) {
  return __uint_as_float(((unsigned)v) << 16);
}
__device__ __forceinline__ void gload_lds16(const void* g, void* l) {
  __builtin_amdgcn_global_load_lds(
      (const __attribute__((address_space(1))) unsigned int*)g,
      (__attribute__((address_space(3))) unsigned int*)l, 16, 0, 0);
}
__device__ __forceinline__ float sigf(float x) { return 1.0f / (1.0f + expf(-x)); }

// lang_id soft-argmax for batch b (all lanes compute same value for same b)
__device__ __forceinline__ float lang_of(const float* __restrict__ logits, int b) {
  float lv[E_];
  float m = -1e30f;
  #pragma unroll
  for (int i = 0; i < E_; ++i) { lv[i] = logits[b * E_ + i]; m = fmaxf(m, lv[i]); }
  float den = 0.f, num = 0.f;
  #pragma unroll
  for (int i = 0; i < E_; ++i) {
    float z = expf((lv[i] - m) * 1000.0f);
    den += z; num += z * (float)i;
  }
  return num / den;
}

// conservative per-expert active flag: gate(e,b)>1e-4 requires |lang-e|<1.6515
__device__ __forceinline__ bool expert_active(const float* __restrict__ logits, int e) {
  int b = threadIdx.x & 15;
  float lang = lang_of(logits, b);
  unsigned long long m = __ballot(fabsf(lang - (float)e) < 1.7f);
  return m != 0ull;  // wave-uniform; identical across waves (b pattern repeats)
}

// ---------------- prep: cvt_x + cvt_w1 + cvt_w2 in one kernel ----------------
// grid = 2048 (x) + 2816 (W1: 11 e x 16 k0 x 16 d0) + 176 (W2: 11 e x 16 k0)
__global__ __launch_bounds__(256) void prep_kernel(
    const float* __restrict__ x, const float* __restrict__ logits,
    const float* __restrict__ W1, const float* __restrict__ W2,
    unsigned short* __restrict__ xbf, unsigned short* __restrict__ W1T,
    unsigned short* __restrict__ W2T) {
  int bid = blockIdx.x;
  int tid = threadIdx.x;
  __shared__ float t[64][65];

  if (bid < 2048) {  // x -> bf16
    int i = (bid * 256 + tid) * 8;
    float4 f0 = *(const float4*)(x + i);
    float4 f1 = *(const float4*)(x + i + 4);
    short8 o;
    o[0] = (short)f2bf(f0.x); o[1] = (short)f2bf(f0.y);
    o[2] = (short)f2bf(f0.z); o[3] = (short)f2bf(f0.w);
    o[4] = (short)f2bf(f1.x); o[5] = (short)f2bf(f1.y);
    o[6] = (short)f2bf(f1.z); o[7] = (short)f2bf(f1.w);
    *(short8*)(xbf + i) = o;
    return;
  }
  if (bid < 2048 + 2816) {  // W1 [e][k][d] -> W1T bf16 [e][d][k]
    int tt = bid - 2048;
    int e = tt >> 8, rest = tt & 255;
    int k0 = (rest >> 4) * 64, d0 = (rest & 15) * 64;
    if (!expert_active(logits, e)) return;
    int kr = tid >> 2, dc = (tid & 3) * 16;
    const float* src = W1 + ((size_t)e << 20) + (size_t)(k0 + kr) * H_ + d0 + dc;
    #pragma unroll
    for (int q = 0; q < 4; ++q) {
      float4 v = *(const float4*)(src + q * 4);
      t[kr][dc + q * 4 + 0] = v.x; t[kr][dc + q * 4 + 1] = v.y;
      t[kr][dc + q * 4 + 2] = v.z; t[kr][dc + q * 4 + 3] = v.w;
    }
    __syncthreads();
    int dr = tid >> 2, kc = (tid & 3) * 16;
    short8 v0, v1;
    #pragma unroll
    for (int j = 0; j < 8; ++j) v0[j] = (short)f2bf(t[kc + j][dr]);
    #pragma unroll
    for (int j = 0; j < 8; ++j) v1[j] = (short)f2bf(t[kc + 8 + j][dr]);
    unsigned short* dst = W1T + ((size_t)e << 20) + (size_t)(d0 + dr) * H_ + k0 + kc;
    *(short8*)(dst) = v0;
    *(short8*)(dst + 8) = v1;
    return;
  }
  {  // W2 [e][k][l] -> W2T bf16 [e][l][k]
    int tt = bid - 4864;
    int e = tt >> 4, k0 = (tt & 15) * 64;
    if (!expert_active(logits, e)) return;
    int kr = tid >> 2, lc = (tid & 3) * 8;
    const float* src = W2 + (size_t)e * H_ * L_ + (size_t)(k0 + kr) * L_ + lc;
    float4 a = *(const float4*)(src);
    float4 b = *(const float4*)(src + 4);
    t[kr][lc + 0] = a.x; t[kr][lc + 1] = a.y; t[kr][lc + 2] = a.z; t[kr][lc + 3] = a.w;
    t[kr][lc + 4] = b.x; t[kr][lc + 5] = b.y; t[kr][lc + 6] = b.z; t[kr][lc + 7] = b.w;
    __syncthreads();
    int lr = tid >> 3, kc = (tid & 7) * 8;
    short8 v;
    #pragma unroll
    for (int j = 0; j < 8; ++j) v[j] = (short)f2bf(t[kc + j][lr]);
    *(short8*)(W2T + (size_t)(e * L_ + lr) * H_ + k0 + kc) = v;
  }
}

// ---------------- fused gated FFN: one block per (e, b, dt, sblk) ----------------
// No XCD pinning (locality proven non-binding); natural enumeration spreads active
// runs of 16 evenly. 2-phase pipeline: stage at top, setprio'd MFMA, vmcnt(0)+barrier
// at bottom only. Partial t atomicAdd'ed; b2 added only by dt==0 blocks.
__global__ __launch_bounds__(256, 4) void ffn_kernel(
    const unsigned short* __restrict__ xbf, const unsigned short* __restrict__ W1T,
    const unsigned short* __restrict__ W2T, const float* __restrict__ b1,
    const float* __restrict__ b2, const float* __restrict__ logits,
    float* __restrict__ out) {
  int bid = blockIdx.x;
  int pid = bid >> 4;            // (e,b) pair [0,176)
  int q = bid & 15;
  int e = pid >> 4, b = pid & 15;
  int dt = q >> 2, sblk = q & 3, s0 = sblk * 64;
  float lang = lang_of(logits, b);
  float fe = (float)e;
  float g = sigf((lang - (fe - 0.5f)) * 8.0f) * sigf(((fe + 0.5f) - lang) * 8.0f);
  if (g < GEPS) return;

  __shared__ __align__(16) char smem[40960];
  char* sA = smem;         // 2 x 4096
  char* sB = smem + 8192;  // 2 x 16384

  int tid = threadIdx.x;
  int w = tid >> 6, l = tid & 63;
  int l15 = l & 15, l4 = l >> 4;

  auto stage = [&](int buf, int kt) {
    {  // A tile: 256 chunks, 1 per lane
      int c = tid;
      int p = c >> 3, slot = c & 7;
      int uu = slot ^ (p & 7);
      int srow = p * 2 + (uu >> 2), kc = uu & 3;
      const unsigned short* src =
          xbf + (size_t)(b * S_ + s0 + srow) * H_ + kt * 32 + kc * 8;
      gload_lds16(src, sA + buf * 4096 + c * 16);
    }
    #pragma unroll
    for (int jj = 0; jj < 4; ++jj) {  // B tile: 1024 chunks, 4 per lane
      int c = jj * 256 + tid;
      int p = c >> 3, slot = c & 7;
      int uu = slot ^ (p & 7);
      int d = p * 2 + (uu >> 2), kc = uu & 3;
      const unsigned short* src =
          W1T + ((size_t)e * H_ + dt * 256 + d) * H_ + kt * 32 + kc * 8;
      gload_lds16(src, sB + buf * 16384 + c * 16);
    }
  };

  float b1v[4];
  #pragma unroll
  for (int nf = 0; nf < 4; ++nf)
    b1v[nf] = b1[e * H_ + dt * 256 + w * 64 + nf * 16 + l15];

  f32x4 acc[4][4];
  #pragma unroll
  for (int mf = 0; mf < 4; ++mf)
    #pragma unroll
    for (int nf = 0; nf < 4; ++nf) acc[mf][nf] = f32x4{0.f, 0.f, 0.f, 0.f};

  stage(0, 0);
  asm volatile("s_waitcnt vmcnt(0)" ::: "memory");
  __builtin_amdgcn_s_barrier();

  #pragma unroll 2
  for (int kt = 0; kt < 32; ++kt) {
    int cur = kt & 1;
    if (kt < 31) stage(cur ^ 1, kt + 1);  // issue next-tile loads early
    short8 af[4], bf[4];
    #pragma unroll
    for (int mf = 0; mf < 4; ++mf) {
      int row = mf * 16 + l15;
      int p = row >> 1;
      int slot = (((row & 1) * 4) + l4) ^ (p & 7);
      af[mf] = *(const short8*)(sA + cur * 4096 + p * 128 + slot * 16);
    }
    #pragma unroll
    for (int nf = 0; nf < 4; ++nf) {
      int d = w * 64 + nf * 16 + l15;
      int p = d >> 1;
      int slot = (((d & 1) * 4) + l4) ^ (p & 7);
      bf[nf] = *(const short8*)(sB + cur * 16384 + p * 128 + slot * 16);
    }
    asm volatile("s_waitcnt lgkmcnt(0)" ::: "memory");
    __builtin_amdgcn_sched_barrier(0);
    __builtin_amdgcn_s_setprio(1);
    #pragma unroll
    for (int mf = 0; mf < 4; ++mf)
      #pragma unroll
      for (int nf = 0; nf < 4; ++nf)
        acc[mf][nf] =
            __builtin_amdgcn_mfma_f32_16x16x32_bf16(af[mf], bf[nf], acc[mf][nf], 0, 0, 0);
    __builtin_amdgcn_s_setprio(0);
    asm volatile("s_waitcnt vmcnt(0)" ::: "memory");
    __builtin_amdgcn_s_barrier();
  }

  // relu(acc + b1) -> bf16 P strip in LDS (overlay on sB, per-wave private 8KB)
  char* P = sB + w * 8192;
  #pragma unroll
  for (int mf = 0; mf < 4; ++mf)
    #pragma unroll
    for (int nf = 0; nf < 4; ++nf)
      #pragma unroll
      for (int rr = 0; rr < 4; ++rr) {
        int row = mf * 16 + l4 * 4 + rr;
        int col = nf * 16 + l15;
        float v = fmaxf(acc[mf][nf][rr] + b1v[nf], 0.f);
        *(unsigned short*)(P + row * 128 + (((col >> 3) ^ (row & 7)) * 16) +
                           (col & 7) * 2) = f2bf(v);
      }
  asm volatile("s_waitcnt lgkmcnt(0)" ::: "memory");

  // stage 2: t_partial = P @ W2T-slice (K = this wave's 64 d's)
  f32x4 tacc[4][2];
  #pragma unroll
  for (int mf = 0; mf < 4; ++mf)
    #pragma unroll
    for (int nf = 0; nf < 2; ++nf) tacc[mf][nf] = f32x4{0.f, 0.f, 0.f, 0.f};
  #pragma unroll
  for (int kk = 0; kk < 2; ++kk) {
    short8 ap[4], bw[2];
    #pragma unroll
    for (int mf = 0; mf < 4; ++mf) {
      int row = mf * 16 + l15;
      int ch = kk * 4 + l4;
      ap[mf] = *(const short8*)(P + row * 128 + ((ch ^ (row & 7)) * 16));
    }
    #pragma unroll
    for (int nf = 0; nf < 2; ++nf)
      bw[nf] = *(const short8*)(W2T + (size_t)(e * L_ + nf * 16 + l15) * H_ +
                                dt * 256 + w * 64 + kk * 32 + l4 * 8);
    #pragma unroll
    for (int mf = 0; mf < 4; ++mf)
      #pragma unroll
      for (int nf = 0; nf < 2; ++nf)
        tacc[mf][nf] =
            __builtin_amdgcn_mfma_f32_16x16x32_bf16(ap[mf], bw[nf], tacc[mf][nf], 0, 0, 0);
  }

  // cross-wave reduce of t_partial, (+ b2 if dt==0), * gate, atomicAdd to out
  float* Tred = (float*)sB;
  #pragma unroll
  for (int mf = 0; mf < 4; ++mf)
    #pragma unroll
    for (int nf = 0; nf < 2; ++nf)
      #pragma unroll
      for (int rr = 0; rr < 4; ++rr) {
        int row = mf * 16 + l4 * 4 + rr;
        int col = nf * 16 + l15;
        Tred[w * 2048 + row * 32 + col] = tacc[mf][nf][rr];
      }
  __syncthreads();
  #pragma unroll
  for (int jj = 0; jj < 8; ++jj) {
    int ei = tid + jj * 256;
    int srow = ei >> 5, lcol = ei & 31;
    float sum = Tred[ei] + Tred[2048 + ei] + Tred[4096 + ei] + Tred[6144 + ei];
    if (dt == 0) sum += b2[e * L_ + lcol];
    atomicAdd(out + (size_t)(b * S_ + s0 + srow) * L_ + lcol, g * sum);
  }
}

// ---------------- fp32 fallback (no workspace needed) ----------------
__global__ void fb_kernel(const float* __restrict__ x, const float* __restrict__ logits,
                          const float* __restrict__ W1, const float* __restrict__ b1,
                          const float* __restrict__ W2, const float* __restrict__ b2,
                          float* __restrict__ out) {
  int bid = blockIdx.x;
  int e = bid >> 9;
  int r = bid & 511;
  int b = r >> 5, st = r & 31, s0 = st * 8;
  float lang = lang_of(logits, b);
  float fe = (float)e;
  float g = sigf((lang - (fe - 0.5f)) * 8.0f) * sigf(((fe + 0.5f) - lang) * 8.0f);
  if (g < GEPS) return;

  __shared__ float xs[8][H_];
  __shared__ unsigned short hs[8][H_];
  int tid = threadIdx.x;
  for (int jj = 0; jj < 32; ++jj) {
    int idx = tid + jj * 256;
    int s = idx >> 10, k = idx & 1023;
    xs[s][k] = x[(size_t)(b * S_ + s0 + s) * H_ + k];
  }
  __syncthreads();
  for (int qq = 0; qq < 4; ++qq) {
    int d = tid + qq * 256;
    float a[8];
    #pragma unroll
    for (int s = 0; s < 8; ++s) a[s] = 0.f;
    for (int k = 0; k < H_; ++k) {
      float wv = W1[((size_t)e << 20) + (size_t)k * H_ + d];
      #pragma unroll
      for (int s = 0; s < 8; ++s) a[s] += xs[s][k] * wv;
    }
    float bv = b1[e * H_ + d];
    #pragma unroll
    for (int s = 0; s < 8; ++s) hs[s][d] = f2bf(fmaxf(a[s] + bv, 0.f));
  }
  __syncthreads();
  int s = tid >> 5, lcol = tid & 31;
  float acc = 0.f;
  for (int d = 0; d < H_; ++d)
    acc += bf2f(hs[s][d]) * W2[(size_t)(e * H_ + d) * L_ + lcol];
  acc += b2[e * L_ + lcol];
  atomicAdd(out + (size_t)(b * S_ + s0 + s) * L_ + lcol, g * acc);
}

extern "C" void kernel_launch(void* const* d_in, const int* in_sizes, int n_in,
                              void* d_out, int out_size, void* d_ws, size_t ws_size,
                              hipStream_t stream) {
  (void)in_sizes; (void)n_in;
  const float* x  = (const float*)d_in[0];
  const float* lg = (const float*)d_in[1];
  const float* W1 = (const float*)d_in[2];
  const float* b1 = (const float*)d_in[3];
  const float* W2 = (const float*)d_in[4];
  const float* b2 = (const float*)d_in[5];
  float* out = (float*)d_out;

  hipMemsetAsync(d_out, 0, (size_t)out_size * sizeof(float), stream);

  const size_t OFF_X = 0;                          // 8 MB bf16 x
  const size_t OFF_W1 = OFF_X + 8388608;           // 22 MB bf16 W1T
  const size_t OFF_W2 = OFF_W1 + 23068672;         // 704 KB bf16 W2T
  const size_t WS_NEED = OFF_W2 + 720896;

  if (ws_size >= WS_NEED) {
    unsigned short* xbf = (unsigned short*)((char*)d_ws + OFF_X);
    unsigned short* W1T = (unsigned short*)((char*)d_ws + OFF_W1);
    unsigned short* W2T = (unsigned short*)((char*)d_ws + OFF_W2);
    prep_kernel<<<2048 + 2816 + 176, 256, 0, stream>>>(x, lg, W1, W2, xbf, W1T, W2T);
    ffn_kernel<<<2816, 256, 0, stream>>>(xbf, W1T, W2T, b1, b2, lg, out);
  } else {
    fb_kernel<<<E_ * B_ * (S_ / 8), 256, 0, stream>>>(x, lg, W1, b1, W2, b2, out);
  }
}